// Round 1
// 1473.111 us; speedup vs baseline: 1.4875x; 1.4875x over previous
//
#include <hip/hip_runtime.h>
#include <math.h>

// ---------------------------------------------------------------------------
// CrossAttentionLayer_convk3s2 — FP32 inputs/outputs, bf16 MFMA internally.
// R1: kmain rewritten as resident-tile kernel:
//   - tgt tile (216x128) staged ONCE into LDS (bf16, XOR-swizzled) + zero row
//   - row-remap tables replace all window/tap re-stagings (24 stagings -> 1)
//   - fine branch batched across 6 windows (4 barriers instead of ~24)
//   - C3 rt double-buffered (1 barrier/tap); G/cwvT read from global (L2-hot)
//   - 512 threads, __launch_bounds__(512,4): 2 blocks/CU -> 16 waves/CU
// k0a/k0b/kffn unchanged from previous round.
// ---------------------------------------------------------------------------

typedef short   mfrag  __attribute__((ext_vector_type(8)));   // 8 x bf16 bits
typedef float   floatx4 __attribute__((ext_vector_type(4)));
typedef unsigned short us4 __attribute__((ext_vector_type(4)));
typedef unsigned int u32x4 __attribute__((ext_vector_type(4)));

#define LL   216     // 12*18 tokens
#define LC   54      // 6*9 coarse positions
#define TP1  136     // pitch (ushorts) for 128-col LDS rows (272B)
#define TP2  72      // pitch (ushorts) for 64-col LDS rows

__device__ __forceinline__ float b2f(unsigned short u){
  return __uint_as_float(((unsigned int)u) << 16);
}
__device__ __forceinline__ unsigned short f2b(float f){
  unsigned int x = __float_as_uint(f);
  return (unsigned short)((x + 0x7fffu + ((x >> 16) & 1u)) >> 16);
}
__device__ __forceinline__ floatx4 mfma16(mfrag a, mfrag b, floatx4 c){
  return __builtin_amdgcn_mfma_f32_16x16x32_bf16(a, b, c, 0, 0, 0);
}
__device__ __forceinline__ mfrag zfrag(){ mfrag z = {0,0,0,0,0,0,0,0}; return z; }

union F8 { unsigned short u[8]; mfrag v; };

struct Par {
  const float *query,*tgt,*ln1g,*ln1b,*ln2g,*ln2b,*wq,*bq,*wk,*wv,*bv,
              *wp,*bp,*f1w,*f1b,*f2w,*f2b,*cw,*cb;
  const float *ln1cg,*ln1cb,*ln2cg,*ln2cb,*wqc,*bqc,*wkc,*wvc,*bvc,
              *wpc,*bpc,*f1cw,*f1cb,*f2cw,*f2cb;
  unsigned short *U;      // [48][128] bf16: fine score vectors (0.25 * wk @ q_head)
  float          *uc;     // [32][128] f32: coarse score vectors pre-conv-fold
  float          *cvb;    // [128] f32: cb@wvc + bvc
  unsigned short *G;      // [9][32][128] bf16: cw_tap-folded coarse score vectors
  unsigned short *cwvT;   // [9][128 d][128 e] bf16: (cw_tap @ wvc) transposed
  unsigned short *wT;     // 6 x [128][128] bf16 transposed: wp,f1,f2,wpc,f1c,f2c
  float          *out;    // [4096*10][128] f32: att staged here, then final
};

// ------------------------------ K0a: tiny precompute (1 block) --------------
__global__ __launch_bounds__(256) void k0a(Par p){
  __shared__ float qn[10][128];
  __shared__ float qp[10][128];
  int tid = threadIdx.x;
  if (tid < 10){
    int r = tid;
    const float* row = p.query + r*128;
    float s1=0.f, s2=0.f;
    for (int c=0;c<128;c++){ float v=row[c]; s1+=v; s2+=v*v; }
    float m = s1/128.f, var = s2/128.f - m*m;
    float inv = rsqrtf(var + 1e-5f);
    const float* g  = (r<6)? p.ln1g : p.ln1cg;
    const float* bb = (r<6)? p.ln1b : p.ln1cb;
    for (int c=0;c<128;c++) qn[r][c] = (row[c]-m)*inv*g[c] + bb[c];
  }
  __syncthreads();
  for (int o=tid;o<1280;o+=256){
    int i=o>>7, d=o&127;
    const float* w  = (i<6)? p.wq : p.wqc;
    const float* bi = (i<6)? p.bq : p.bqc;
    float acc = bi[d];
    for (int c=0;c<128;c++) acc += qn[i][c]*w[c*128+d];
    qp[i][d]=acc;
  }
  __syncthreads();
  // fine score vectors u[ih][c] = 0.25 * sum_dd wk[c][h*16+dd]*q[i][h*16+dd]
  for (int o=tid;o<6144;o+=256){
    int ih=o>>7, c=o&127, i=ih>>3, h=ih&7;
    float a=0.f;
    for (int dd=0;dd<16;dd++) a += p.wk[c*128 + h*16+dd] * qp[i][h*16+dd];
    p.U[ih*128+c] = f2b(0.25f*a);
  }
  // coarse (pre-conv-fold), kept fp32 for K0b
  for (int o=tid;o<4096;o+=256){
    int ih=o>>7, c=o&127, i=ih>>3, h=ih&7;
    float a=0.f;
    for (int dd=0;dd<16;dd++) a += p.wkc[c*128 + h*16+dd] * qp[6+i][h*16+dd];
    p.uc[ih*128+c] = 0.25f*a;
  }
  if (tid < 128){
    int d = tid; float a = p.bvc[d];
    for (int c=0;c<128;c++) a += p.cb[c] * p.wvc[c*128+d];
    p.cvb[d] = a;
  }
}

// --------------------- K0b: folded weights (24 blocks) ----------------------
__global__ __launch_bounds__(256) void k0b(Par p){
  int bid = blockIdx.x, tid = threadIdx.x;
  if (bid < 9){            // G[tap][ih][e] = sum_c cw[tap][e][c]*uc[ih][c]
    int tap = bid;
    for (int o=tid;o<4096;o+=256){
      int ih=o>>7, e=o&127; float a=0.f;
      const float* cwr = p.cw + (tap*128+e)*128;
      const float* ucr = p.uc + ih*128;
      for (int c=0;c<128;c++) a += cwr[c]*ucr[c];
      p.G[(tap*32+ih)*128 + e] = f2b(a);
    }
  } else if (bid < 18){    // cwvT[tap][d][e] = sum_c cw[tap][e][c]*wvc[c][d]
    int tap = bid-9;
    for (int o=tid;o<16384;o+=256){
      int d=o>>7, e=o&127; float a=0.f;
      const float* cwr = p.cw + (tap*128+e)*128;
      for (int c=0;c<128;c++) a += cwr[c]*p.wvc[c*128+d];
      p.cwvT[(tap*128+d)*128 + e] = f2b(a);
    }
  } else {                 // transposed FFN weights (f32 -> bf16)
    int j = bid-18;
    const float* src;
    switch(j){ case 0: src=p.wp;  break; case 1: src=p.f1w;  break;
               case 2: src=p.f2w; break; case 3: src=p.wpc;  break;
               case 4: src=p.f1cw;break; default: src=p.f2cw; }
    unsigned short* dst = p.wT + j*16384;
    for (int o=tid;o<16384;o+=256){ int n=o>>7,k=o&127; dst[o] = f2b(src[k*128+n]); }
  }
}

// ------------------------------ MAIN: one batch per block -------------------
// LDS map (79,488 B total -> 2 blocks/CU):
//   [     0, 55552)  tile  : [217][128] bf16, row 216 = zeros, XOR-swizzled
//   [ 55552, 56704)  rmap  : [9 taps][64 pos] u16 tile-row (216 = zero row)
//   [ 56704, 57472)  rmapF : [6 win][64 lw]   u16 tile-row (216 = zero row)
//   [ 57472, 79488)  regn  : 22,016 B phase-unioned scratch
//     fine  : sf [216][9] f32 (7776) overlaid by rbA [48][136] bf16 (13056);
//             aw [48][72] bf16 at +13056 (6912)
//     coarse: ac [32][72] bf16 at +0 (4608); sct [54][33] f32 at +4608 (7128,
//             inside rt0); rt0 at +4608 (8704); rt1 at +13312 (8704)
__global__ __launch_bounds__(512, 4) void kmain(Par p){
  __shared__ __align__(16) unsigned char smem[79488];
  unsigned short* tile  = (unsigned short*)smem;
  unsigned short* rmap  = (unsigned short*)(smem + 55552);
  unsigned short* rmapF = (unsigned short*)(smem + 56704);
  unsigned char*  regn  = smem + 57472;
  float*          sf    = (float*)regn;                     // [216][9]
  unsigned short* rbA   = (unsigned short*)regn;            // [48][136]
  unsigned short* aw    = (unsigned short*)(regn + 13056);  // [48][72]
  unsigned short* ac    = (unsigned short*)regn;            // [32][72]
  float*          sct   = (float*)(regn + 4608);            // [54][33]
  unsigned short* rt0   = (unsigned short*)(regn + 4608);   // [32][136]
  unsigned short* rt1   = (unsigned short*)(regn + 13312);  // [32][136]

  int tid  = threadIdx.x;
  int b    = blockIdx.x;
  int lane = tid & 63, wvx = tid >> 6;          // 8 waves
  int q4   = lane >> 4, n16 = lane & 15;
  const float* tb = p.tgt + (size_t)b*LL*128;

  // swizzled-tile accessors
  auto tfrag = [&](int row, int kb)->mfrag {    // kb: 16B-aligned byte col
    return *reinterpret_cast<const mfrag*>(
        (unsigned char*)tile + row*256 + (kb ^ ((row & 7) << 4)));
  };
  auto tld = [&](int row, int col)->unsigned short {  // col in ushorts
    int byte = (col*2) ^ ((row & 7) << 4);
    return tile[row*128 + (byte >> 1)];
  };

  // ---- stage tile once (f32 -> bf16, swizzled), fill remap tables ----------
  for (int o = tid; o < 217*32; o += 512){
    int row = o >> 5, c4 = o & 31;
    float4 v = make_float4(0.f,0.f,0.f,0.f);
    if (row < 216) v = *reinterpret_cast<const float4*>(tb + row*128 + c4*4);
    us4 w = { f2b(v.x), f2b(v.y), f2b(v.z), f2b(v.w) };
    int byte = (c4*8) ^ ((row & 7) << 4);
    *reinterpret_cast<us4*>((unsigned char*)tile + row*256 + byte) = w;
  }
  for (int o = tid; o < 960; o += 512){
    if (o < 576){                       // rmap[tap][pos]
      int tap = o >> 6, pos = o & 63;
      int ip = pos/9, jp = pos - ip*9;
      int r = ip*2 + tap/3 - 1, c = jp*2 + (tap%3) - 1;
      rmap[o] = (pos < 54 && r >= 0 && r < 12 && c >= 0 && c < 18)
                ? (unsigned short)(r*18 + c) : (unsigned short)216;
    } else {                            // rmapF[win][lw]
      int t = o - 576; int win = t >> 6, lw = t & 63;
      int r0 = (win/3)*6, c0 = (win%3)*6;
      rmapF[t] = (lw < 36) ? (unsigned short)((r0 + lw/6)*18 + c0 + lw%6)
                           : (unsigned short)216;
    }
  }
  __syncthreads();

  // ===================== FINE: all 6 windows batched ========================
  // F1: scores S[win][l][h] = T[row(win,l)] . U[win*8+h]
  for (int task = wvx; task < 18; task += 8){
    int win = task/3, rg = task - win*3;
    int lw = rg*16 + n16;
    int trow = rmapF[win*64 + lw];
    floatx4 acc = {0.f,0.f,0.f,0.f};
    #pragma unroll
    for (int ks=0; ks<4; ks++){
      mfrag a = tfrag(trow, ks*64 + q4*16);
      mfrag bf = zfrag();
      if (n16 < 8) bf = *reinterpret_cast<const mfrag*>(p.U + (win*8+n16)*128 + ks*32 + q4*8);
      acc = mfma16(a, bf, acc);
    }
    if (n16 < 8){
      #pragma unroll
      for (int r=0;r<4;r++){
        int l = rg*16 + q4*4 + r;
        if (l < 36) sf[(win*36+l)*9 + n16] = acc[r];
      }
    }
  }
  __syncthreads();
  // F2: softmax, 48 parallel (win,h) rows
  if (tid < 48){
    int win = tid >> 3;
    float* base = sf + win*36*9 + (tid & 7);
    float mx = -1e30f;
    for (int l=0;l<36;l++) mx = fmaxf(mx, base[l*9]);
    float sm = 0.f;
    for (int l=0;l<36;l++){ float e = __expf(base[l*9]-mx); sm += e; base[l*9] = e; }
    float inv = 1.f/sm;
    for (int l=0;l<64;l++) aw[tid*TP2 + l] = (l<36) ? f2b(base[l*9]*inv) : (unsigned short)0;
  }
  __syncthreads();
  // F3: PV  rbA[win*8+h][d] = sum_l aw[win*8+h][l] * T[row(win,l)][d]
  {
    int nt = wvx;   // 16-col slice per wave
    for (int win=0; win<6; win++){
      floatx4 acc = {0.f,0.f,0.f,0.f};
      #pragma unroll
      for (int ks=0; ks<2; ks++){
        mfrag a = zfrag();
        if (n16 < 8) a = *reinterpret_cast<const mfrag*>(aw + (win*8+n16)*TP2 + ks*32 + q4*8);
        F8 bb;
        #pragma unroll
        for (int j=0;j<8;j++){
          int lw = ks*32 + q4*8 + j;
          bb.u[j] = tld(rmapF[win*64 + lw], nt*16 + n16);
        }
        acc = mfma16(a, bb.v, acc);
      }
      #pragma unroll
      for (int r=0;r<4;r++){
        int h = q4*4 + r;
        if (h < 8) rbA[(win*8+h)*TP1 + nt*16 + n16] = f2b(acc[r]);
      }
    }
  }
  __syncthreads();
  // F4: out[win][d] = sum_c rbA[win*8+h(d)][c]*wv[c][d] + bv[d]  (wv kept f32)
  for (int o = tid; o < 768; o += 512){
    int win = o >> 7, d = o & 127, h = d >> 4;
    const unsigned short* rp = rbA + (win*8+h)*TP1;
    float acc = p.bv[d];
    #pragma unroll 4
    for (int c=0;c<128;c++) acc += b2f(rp[c]) * p.wv[c*128 + d];
    p.out[((size_t)b*10 + win)*128 + d] = acc;
  }
  __syncthreads();

  // =================== COARSE scores: 9 taps from resident tile =============
  {
    int g = wvx >> 1, nt = wvx & 1;
    int pos = g*16 + n16;
    floatx4 acc = {0.f,0.f,0.f,0.f};
    for (int tap=0; tap<9; tap++){
      int trow = rmap[tap*64 + pos];
      #pragma unroll
      for (int ks=0; ks<4; ks++){
        mfrag a = tfrag(trow, ks*64 + q4*16);
        mfrag bf = *reinterpret_cast<const mfrag*>(
            p.G + (size_t)(tap*32 + nt*16 + n16)*128 + ks*32 + q4*8);
        acc = mfma16(a, bf, acc);
      }
    }
    #pragma unroll
    for (int r=0;r<4;r++){
      int l = g*16 + q4*4 + r;
      if (l < LC) sct[l*33 + nt*16 + n16] = acc[r];
    }
  }
  __syncthreads();
  // C2: softmax per (i,h) over its window (masked full-K weights into ac)
  if (tid < 32){
    int i = tid>>3;
    int rA = (i>>1)*3, cA = (i&1)*4, cB = (i&1)? 9 : 4;
    float mx = -1e30f;
    for (int r=rA;r<rA+3;r++) for (int c=cA;c<cB;c++)
      mx = fmaxf(mx, sct[(r*9+c)*33 + tid]);
    float sm=0.f;
    for (int r=rA;r<rA+3;r++) for (int c=cA;c<cB;c++){
      int l=r*9+c; float e=__expf(sct[l*33+tid]-mx); sm+=e; sct[l*33+tid]=e;
    }
    float inv=1.f/sm;
    for (int l=0;l<64;l++){
      unsigned short v = 0;
      if (l < LC){
        int r = l/9, c = l - r*9;
        if (r>=rA && r<rA+3 && c>=cA && c<cB) v = f2b(sct[l*33+tid]*inv);
      }
      ac[tid*TP2 + l] = v;
    }
  }
  __syncthreads();
  // C3: per tap PV -> rt (double-buffered, 1 barrier/tap), proj by cwvT,
  //     accumulate out_c[i][d] across taps in registers.
  {
    floatx4 pacc = {0.f,0.f,0.f,0.f};
    int h = wvx, nt = wvx;
    for (int tap=0; tap<9; tap++){
      unsigned short* rtw = (tap & 1) ? rt1 : rt0;
      // PV: rt[ih][e] = sum_pos ac[ih][pos] * T[rmap(tap,pos)][e]
      F8 b0, b1;
      #pragma unroll
      for (int j=0;j<8;j++){
        b0.u[j] = tld(rmap[tap*64 +      q4*8 + j], nt*16 + n16);
        b1.u[j] = tld(rmap[tap*64 + 32 + q4*8 + j], nt*16 + n16);
      }
      #pragma unroll
      for (int mt=0; mt<2; mt++){
        mfrag a0 = *reinterpret_cast<const mfrag*>(ac + (mt*16+n16)*TP2 +      q4*8);
        mfrag a1 = *reinterpret_cast<const mfrag*>(ac + (mt*16+n16)*TP2 + 32 + q4*8);
        floatx4 rr = {0.f,0.f,0.f,0.f};
        rr = mfma16(a0, b0.v, rr);
        rr = mfma16(a1, b1.v, rr);
        #pragma unroll
        for (int r=0;r<4;r++){
          int ih = mt*16 + q4*4 + r;
          rtw[ih*TP1 + nt*16 + n16] = f2b(rr[r]);
        }
      }
      __syncthreads();
      // proj: pacc[i][j] += sum_e rt[i*8+h][e] * cwvT[tap][h*16+j][e]
      #pragma unroll
      for (int ks=0; ks<4; ks++){
        mfrag a = zfrag();
        if (n16 < 4) a = *reinterpret_cast<const mfrag*>(rtw + (n16*8 + h)*TP1 + ks*32 + q4*8);
        mfrag bf = *reinterpret_cast<const mfrag*>(
            p.cwvT + ((size_t)tap*128 + h*16 + n16)*128 + ks*32 + q4*8);
        pacc = mfma16(a, bf, pacc);
      }
      // next tap's PV writes the other rt buffer; the barrier above separates
      // proj(t) from PV(t+2)'s overwrite of this buffer.
    }
    if (q4 == 0){
      #pragma unroll
      for (int r=0;r<4;r++){
        int d = h*16 + n16;
        p.out[((size_t)b*10 + 6 + r)*128 + d] = pacc[r] + p.cvb[d];
      }
    }
  }
}

// ------------------- K2: proj + residual + LN + GELU FFN --------------------
// Reads 64 att rows (f32) from d_out, writes final values back to same rows.
__global__ __launch_bounds__(256) void kffn(Par p){
  __shared__ alignas(16) unsigned short ba[64*TP1];   // bf16 work buffer
  __shared__ alignas(16) unsigned short bbq[64*TP1];  // bf16 work buffer
  __shared__ alignas(16) unsigned short xb[64*TP1];   // bf16 pre-LN residual x
  int tid=threadIdx.x, bid=blockIdx.x;
  int lane=tid&63, wvv=tid>>6, q4=lane>>4, n16=lane&15;
  bool fine = bid < 384;
  int rows0 = fine? bid*64 : (bid-384)*64;
  int TPB = fine? 6 : 4, toff = fine? 0 : 6;
  const unsigned short* w1 = p.wT + (fine?0:3)*16384;
  const unsigned short* w2 = p.wT + (fine?1:4)*16384;
  const unsigned short* w3 = p.wT + (fine?2:5)*16384;
  const float* bi1 = fine? p.bp  : p.bpc;
  const float* bi2 = fine? p.f1b : p.f1cb;
  const float* bi3 = fine? p.f2b : p.f2cb;
  const float* g2  = fine? p.ln2g : p.ln2cg;
  const float* be2 = fine? p.ln2b : p.ln2cb;

  for (int ci=tid; ci<64*32; ci+=256){
    int row=ci>>5, c4=ci&31;
    int grow = rows0 + row;
    int bglob = grow / TPB, t = toff + (grow % TPB);
    float4 v = *reinterpret_cast<const float4*>(p.out + ((size_t)bglob*10+t)*128 + c4*4);
    us4 o = { f2b(v.x), f2b(v.y), f2b(v.z), f2b(v.w) };
    *reinterpret_cast<us4*>(ba + row*TP1 + c4*4) = o;
  }
  __syncthreads();
  { // x = sc + att@wp + bp   (store x as bf16 in xb)
    mfrag A[4];
    #pragma unroll
    for (int ks=0;ks<4;ks++) A[ks] = *reinterpret_cast<const mfrag*>(ba + (wvv*16+n16)*TP1 + ks*32+q4*8);
    for (int nt=0;nt<8;nt++){
      floatx4 acc={0.f,0.f,0.f,0.f};
      #pragma unroll
      for (int ks=0;ks<4;ks++){
        mfrag Bf = *reinterpret_cast<const mfrag*>(w1 + (nt*16+n16)*128 + ks*32+q4*8);
        acc = mfma16(A[ks], Bf, acc);
      }
      #pragma unroll
      for (int r=0;r<4;r++){
        int row = wvv*16+q4*4+r;
        int grow = rows0 + row;
        int t = toff + (grow % TPB);
        int d = nt*16+n16;
        xb[row*TP1+d] = f2b(acc[r] + bi1[d] + p.query[t*128+d]);
      }
    }
  }
  __syncthreads();
  if (tid < 64){ // LayerNorm over x
    int row=tid; float s1=0.f,s2=0.f;
    for (int c=0;c<128;c++){ float v=b2f(xb[row*TP1+c]); s1+=v; s2+=v*v; }
    float m=s1/128.f, var=s2/128.f-m*m, inv=rsqrtf(var+1e-5f);
    for (int c=0;c<128;c++){
      float v=(b2f(xb[row*TP1+c])-m)*inv*g2[c]+be2[c];
      bbq[row*TP1+c]=f2b(v);
    }
  }
  __syncthreads();
  { // h = gelu(xn@f1 + b1)
    mfrag A[4];
    #pragma unroll
    for (int ks=0;ks<4;ks++) A[ks] = *reinterpret_cast<const mfrag*>(bbq + (wvv*16+n16)*TP1 + ks*32+q4*8);
    for (int nt=0;nt<8;nt++){
      floatx4 acc={0.f,0.f,0.f,0.f};
      #pragma unroll
      for (int ks=0;ks<4;ks++){
        mfrag Bf = *reinterpret_cast<const mfrag*>(w2 + (nt*16+n16)*128 + ks*32+q4*8);
        acc = mfma16(A[ks], Bf, acc);
      }
      #pragma unroll
      for (int r=0;r<4;r++){
        int row=wvv*16+q4*4+r, d=nt*16+n16;
        float v = acc[r] + bi2[d];
        ba[row*TP1+d] = f2b(0.5f*v*(1.f+erff(v*0.70710678118f)));
      }
    }
  }
  __syncthreads();
  { // out = x + h@f2 + b2   (f32 out)
    mfrag A[4];
    #pragma unroll
    for (int ks=0;ks<4;ks++) A[ks] = *reinterpret_cast<const mfrag*>(ba + (wvv*16+n16)*TP1 + ks*32+q4*8);
    for (int nt=0;nt<8;nt++){
      floatx4 acc={0.f,0.f,0.f,0.f};
      #pragma unroll
      for (int ks=0;ks<4;ks++){
        mfrag Bf = *reinterpret_cast<const mfrag*>(w3 + (nt*16+n16)*128 + ks*32+q4*8);
        acc = mfma16(A[ks], Bf, acc);
      }
      #pragma unroll
      for (int r=0;r<4;r++){
        int row=wvv*16+q4*4+r, d=nt*16+n16;
        int grow=rows0+row;
        int bglob = grow / TPB, t = toff + (grow % TPB);
        p.out[((size_t)bglob*10+t)*128+d] = b2f(xb[row*TP1+d]) + acc[r] + bi3[d];
      }
    }
  }
}

// ---------------------------------------------------------------------------
extern "C" void kernel_launch(void* const* d_in, const int* in_sizes, int n_in,
                              void* d_out, int out_size, void* d_ws, size_t ws_size,
                              hipStream_t stream){
  (void)in_sizes; (void)n_in; (void)out_size; (void)ws_size;
  Par p;
  p.query=(const float*)d_in[0];  p.tgt  =(const float*)d_in[1];
  p.ln1g =(const float*)d_in[2];  p.ln1b =(const float*)d_in[3];
  p.ln2g =(const float*)d_in[4];  p.ln2b =(const float*)d_in[5];
  p.wq   =(const float*)d_in[6];  p.bq   =(const float*)d_in[7];
  p.wk   =(const float*)d_in[8];  /* bk d_in[9] unused (softmax-invariant) */
  p.wv   =(const float*)d_in[10]; p.bv   =(const float*)d_in[11];
  p.wp   =(const float*)d_in[12]; p.bp   =(const float*)d_in[13];
  p.f1w  =(const float*)d_in[14]; p.f1b  =(const float*)d_in[15];
  p.f2w  =(const float*)d_in[16]; p.f2b  =(const float*)d_in[17];
  p.cw   =(const float*)d_in[18]; p.cb   =(const float*)d_in[19];
  p.ln1cg=(const float*)d_in[20]; p.ln1cb=(const float*)d_in[21];
  p.ln2cg=(const float*)d_in[22]; p.ln2cb=(const float*)d_in[23];
  p.wqc  =(const float*)d_in[24]; p.bqc  =(const float*)d_in[25];
  p.wkc  =(const float*)d_in[26]; /* bkc d_in[27] unused */
  p.wvc  =(const float*)d_in[28]; p.bvc  =(const float*)d_in[29];
  p.wpc  =(const float*)d_in[30]; p.bpc  =(const float*)d_in[31];
  p.f1cw =(const float*)d_in[32]; p.f1cb =(const float*)d_in[33];
  p.f2cw =(const float*)d_in[34]; p.f2cb =(const float*)d_in[35];
  char* ws = (char*)d_ws;
  p.U    = (unsigned short*)(ws + 0);        //  12,288 B
  p.uc   = (float*)        (ws + 16384);     //  16,384 B
  p.cvb  = (float*)        (ws + 49152);     //     512 B
  p.G    = (unsigned short*)(ws + 65536);    //  73,728 B
  p.cwvT = (unsigned short*)(ws + 147456);   // 294,912 B
  p.wT   = (unsigned short*)(ws + 458752);   // 196,608 B  (ends ~640 KB)
  p.out  = (float*)d_out;

  k0a <<<dim3(1),    dim3(256), 0, stream>>>(p);
  k0b <<<dim3(24),   dim3(256), 0, stream>>>(p);
  kmain<<<dim3(4096), dim3(512), 0, stream>>>(p);
  kffn <<<dim3(640),  dim3(256), 0, stream>>>(p);
}

// Round 2
// 1098.939 us; speedup vs baseline: 1.9940x; 1.3405x over previous
//
#include <hip/hip_runtime.h>
#include <math.h>

// ---------------------------------------------------------------------------
// CrossAttentionLayer_convk3s2 — FP32 in/out, bf16 MFMA internally.
// R2: kmain: premultiplied swizzle-ready rmap tables (1-XOR addressing),
//     wave-parallel softmaxes (F2/C2), F4 as MFMA vs precomputed wvT,
//     C-score fused into F4 phase.  k0b replaced by ktrans (LDS transposes,
//     coalesced) + kfold (MFMA weight folds).  k0a stages wk/wkc in LDS
//     (kills diverged global gathers).  kffn: wave-parallel LayerNorm.
// ---------------------------------------------------------------------------

typedef short   mfrag  __attribute__((ext_vector_type(8)));   // 8 x bf16 bits
typedef float   floatx4 __attribute__((ext_vector_type(4)));
typedef unsigned short us4 __attribute__((ext_vector_type(4)));
typedef unsigned short us8 __attribute__((ext_vector_type(8)));
typedef unsigned int u32x4 __attribute__((ext_vector_type(4)));

#define LL   216     // 12*18 tokens
#define LC   54      // 6*9 coarse positions
#define TP1  136     // pitch (ushorts) for 128-col LDS rows (272B)
#define TP2  72      // pitch (ushorts) for 64-col LDS rows

__device__ __forceinline__ float b2f(unsigned short u){
  return __uint_as_float(((unsigned int)u) << 16);
}
__device__ __forceinline__ unsigned short f2b(float f){
  unsigned int x = __float_as_uint(f);
  return (unsigned short)((x + 0x7fffu + ((x >> 16) & 1u)) >> 16);
}
__device__ __forceinline__ floatx4 mfma16(mfrag a, mfrag b, floatx4 c){
  return __builtin_amdgcn_mfma_f32_16x16x32_bf16(a, b, c, 0, 0, 0);
}
__device__ __forceinline__ mfrag zfrag(){ mfrag z = {0,0,0,0,0,0,0,0}; return z; }

union F8 { unsigned short u[8]; mfrag v; };

struct Par {
  const float *query,*tgt,*ln1g,*ln1b,*ln2g,*ln2b,*wq,*bq,*wk,*wv,*bv,
              *wp,*bp,*f1w,*f1b,*f2w,*f2b,*cw,*cb;
  const float *ln1cg,*ln1cb,*ln2cg,*ln2cb,*wqc,*bqc,*wkc,*wvc,*bvc,
              *wpc,*bpc,*f1cw,*f1cb,*f2cw,*f2cb;
  unsigned short *U;      // [48][128] bf16: fine score vectors (0.25 * wk @ q_head)
  float          *uc;     // [32][128] f32: coarse score vectors pre-conv-fold
  float          *cvb;    // [128] f32: cb@wvc + bvc
  unsigned short *G;      // [9][32][128] bf16: cw_tap-folded coarse score vectors
  unsigned short *cwvT;   // [9][128 d][128 e] bf16: (cw_tap @ wvc) transposed
  unsigned short *wT;     // 8 x [128][128] bf16 transposed: wp,f1,f2,wpc,f1c,f2c,wv,wvc
  float          *out;    // [4096*10][128] f32: att staged here, then final
};

// ------------------------------ K0a: tiny precompute (1 block) --------------
__global__ __launch_bounds__(256) void k0a(Par p){
  __shared__ float qn[10][128];
  __shared__ float qp[10][128];
  __shared__ unsigned short wkb[128*130];
  int tid = threadIdx.x;
  if (tid < 10){
    int r = tid;
    const float* row = p.query + r*128;
    float s1=0.f, s2=0.f;
    for (int c=0;c<128;c++){ float v=row[c]; s1+=v; s2+=v*v; }
    float m = s1/128.f, var = s2/128.f - m*m;
    float inv = rsqrtf(var + 1e-5f);
    const float* g  = (r<6)? p.ln1g : p.ln1cg;
    const float* bb = (r<6)? p.ln1b : p.ln1cb;
    for (int c=0;c<128;c++) qn[r][c] = (row[c]-m)*inv*g[c] + bb[c];
  }
  __syncthreads();
  for (int o=tid;o<1280;o+=256){
    int i=o>>7, d=o&127;
    const float* w  = (i<6)? p.wq : p.wqc;
    const float* bi = (i<6)? p.bq : p.bqc;
    float acc = bi[d];
    for (int c=0;c<128;c++) acc += qn[i][c]*w[c*128+d];
    qp[i][d]=acc;
  }
  if (tid < 128){
    int d = tid; float a = p.bvc[d];
    for (int c=0;c<128;c++) a += p.cb[c] * p.wvc[c*128+d];
    p.cvb[d] = a;
  }
  __syncthreads();
  // stage wk -> LDS bf16 (coalesced), then fine score vectors
  for (int o=tid;o<16384;o+=256) wkb[(o>>7)*130 + (o&127)] = f2b(p.wk[o]);
  __syncthreads();
  for (int o=tid;o<6144;o+=256){
    int ih=o>>7, c=o&127, i=ih>>3, h=ih&7;
    float a=0.f;
    #pragma unroll
    for (int dd=0;dd<16;dd++) a += b2f(wkb[c*130 + h*16+dd]) * qp[i][h*16+dd];
    p.U[ih*128+c] = f2b(0.25f*a);
  }
  __syncthreads();
  for (int o=tid;o<16384;o+=256) wkb[(o>>7)*130 + (o&127)] = f2b(p.wkc[o]);
  __syncthreads();
  for (int o=tid;o<4096;o+=256){
    int ih=o>>7, c=o&127, i=ih>>3, h=ih&7;
    float a=0.f;
    #pragma unroll
    for (int dd=0;dd<16;dd++) a += b2f(wkb[c*130 + h*16+dd]) * qp[6+i][h*16+dd];
    p.uc[ih*128+c] = 0.25f*a;
  }
}

// ---------------- ktrans: 8 bf16 transposes via padded LDS ------------------
// slots: 0 wp, 1 f1w, 2 f2w, 3 wpc, 4 f1cw, 5 f2cw, 6 wv, 7 wvc
__global__ __launch_bounds__(256) void ktrans(Par p){
  __shared__ float lt[128*129];
  int bid = blockIdx.x, tid = threadIdx.x;
  const float* src;
  switch(bid){ case 0: src=p.wp;  break; case 1: src=p.f1w;  break;
               case 2: src=p.f2w; break; case 3: src=p.wpc;  break;
               case 4: src=p.f1cw;break; case 5: src=p.f2cw; break;
               case 6: src=p.wv;  break; default: src=p.wvc; }
  unsigned short* dst = p.wT + bid*16384;
  for (int o=tid;o<16384;o+=256){ int k=o>>7, n=o&127; lt[n*129+k] = src[o]; }
  __syncthreads();
  for (int o=tid;o<16384;o+=256){ int n=o>>7, k=o&127; dst[o] = f2b(lt[n*129+k]); }
}

// ---------------- kfold: G + cwvT via MFMA (18 blocks) ----------------------
__global__ __launch_bounds__(256) void kfold(Par p){
  __shared__ alignas(16) unsigned short cwb[128*136];
  __shared__ alignas(16) unsigned short ucb[32*136];
  int bid=blockIdx.x, tid=threadIdx.x;
  int lane=tid&63, w=tid>>6, q4=lane>>4, n16=lane&15;
  int tap = (bid<9)? bid : bid-9;
  for (int o=tid;o<16384;o+=256)
    cwb[(o>>7)*136 + (o&127)] = f2b(p.cw[(size_t)tap*16384 + o]);
  if (bid < 9){
    // G[tap][ih][e] = sum_c uc[ih][c] * cw[tap][e][c]
    for (int o=tid;o<4096;o+=256) ucb[(o>>7)*136 + (o&127)] = f2b(p.uc[o]);
    __syncthreads();
    #pragma unroll
    for (int nt2=0;nt2<2;nt2++){
      int nt = w + nt2*4;
      #pragma unroll
      for (int mt=0;mt<2;mt++){
        floatx4 acc={0.f,0.f,0.f,0.f};
        #pragma unroll
        for (int ks=0;ks<4;ks++){
          mfrag a  = *reinterpret_cast<const mfrag*>(ucb + (mt*16+n16)*136 + ks*32+q4*8);
          mfrag bf = *reinterpret_cast<const mfrag*>(cwb + (nt*16+n16)*136 + ks*32+q4*8);
          acc = mfma16(a, bf, acc);
        }
        #pragma unroll
        for (int r=0;r<4;r++){
          int ih = mt*16+q4*4+r, e = nt*16+n16;
          p.G[(tap*32+ih)*128 + e] = f2b(acc[r]);
        }
      }
    }
  } else {
    // cwvT[tap][d][e] = sum_c cw[tap][e][c] * wvc[c][d]   (P[e][d] transposed)
    __syncthreads();
    const unsigned short* wvcT = p.wT + 7*16384;
    #pragma unroll 1
    for (int mt=0;mt<8;mt++){
      #pragma unroll
      for (int nt2=0;nt2<2;nt2++){
        int nt = w + nt2*4;
        floatx4 acc={0.f,0.f,0.f,0.f};
        #pragma unroll
        for (int ks=0;ks<4;ks++){
          mfrag a  = *reinterpret_cast<const mfrag*>(cwb + (mt*16+n16)*136 + ks*32+q4*8);
          mfrag bf = *reinterpret_cast<const mfrag*>(wvcT + (nt*16+n16)*128 + ks*32+q4*8);
          acc = mfma16(a, bf, acc);
        }
        us4 pk = { f2b(acc[0]), f2b(acc[1]), f2b(acc[2]), f2b(acc[3]) };
        *reinterpret_cast<us4*>(p.cwvT + ((size_t)tap*128 + nt*16+n16)*128 + mt*16 + q4*4) = pk;
      }
    }
  }
}

// ------------------------------ MAIN: one batch per block -------------------
// LDS map (79,488 B -> 2 blocks/CU):
//   [     0, 55552)  tile  : [217][128] bf16, row 216 = zeros, XOR-swizzled
//   [ 55552, 56704)  rmap  : [9 taps][64 pos] u16 PREMULT addr row*256+((row&7)<<4)
//   [ 56704, 57472)  rmapF : [6 win][64 lw]   u16 PREMULT addr
//   [ 57472, 79488)  regn  : 22,016 B phase-unioned scratch
//     sfT  @+0     [48][40] f32 (7680)   F1 -> F2
//     aw   @+13056 [48][72] u16 (6912)   F2 -> F3
//     rbA  @+0     [48][136] u16 (13056) F3 -> F4
//     sctT @+13056 [32][56] f32 (7168)   Cscore -> C2
//     ac   @+0     [32][72] u16 (4608)   C2 -> C3
//     rt0  @+4608  rt1 @+13312 (8704 ea) C3 double buffer
__global__ __launch_bounds__(512, 4) void kmain(Par p){
  __shared__ __align__(16) unsigned char smem[79488];
  unsigned short* tile  = (unsigned short*)smem;
  unsigned short* rmap  = (unsigned short*)(smem + 55552);
  unsigned short* rmapF = (unsigned short*)(smem + 56704);
  unsigned char*  regn  = smem + 57472;
  float*          sfT   = (float*)regn;                     // [48][40]
  unsigned short* aw    = (unsigned short*)(regn + 13056);  // [48][72]
  unsigned short* rbA   = (unsigned short*)regn;            // [48][136]
  float*          sctT  = (float*)(regn + 13056);           // [32][56]
  unsigned short* ac    = (unsigned short*)regn;            // [32][72]
  unsigned short* rt0   = (unsigned short*)(regn + 4608);
  unsigned short* rt1   = (unsigned short*)(regn + 13312);

  int tid  = threadIdx.x;
  int b    = blockIdx.x;
  int lane = tid & 63, wvx = tid >> 6;          // 8 waves
  int q4   = lane >> 4, n16 = lane & 15;
  const float* tb = p.tgt + (size_t)b*LL*128;
  const unsigned char* tB = (const unsigned char*)tile;

  // A-frag from premultiplied addr ax, compile-time-ish kb (byte col, 16-mult)
  auto tfragX = [&](unsigned ax, int kb)->mfrag {
    return *reinterpret_cast<const mfrag*>(
        tB + ((ax ^ (unsigned)(kb & 0x70)) + (unsigned)(kb & 0xFFFFFF8F)));
  };

  // ---- stage tile once (f32 -> bf16, swizzled), fill premult remap tables --
  {
    int c4 = tid & 31;
    unsigned c8m = (unsigned)((c4*8) & 0x70), c8l = (unsigned)((c4*8) & 0x88);
    for (int o = tid; o < 217*32; o += 512){
      int row = o >> 5;
      float4 v = make_float4(0.f,0.f,0.f,0.f);
      if (row < 216) v = *reinterpret_cast<const float4*>(tb + row*128 + (c4<<2));
      us4 wv4 = { f2b(v.x), f2b(v.y), f2b(v.z), f2b(v.w) };
      unsigned s = (unsigned)((row & 7) << 4);
      unsigned addr = (unsigned)(row*256) + ((c8m ^ s) + c8l);
      *reinterpret_cast<us4*>((unsigned char*)tile + addr) = wv4;
    }
  }
  for (int o = tid; o < 960; o += 512){
    int row;
    if (o < 576){                       // rmap[tap][pos]
      int tap = o >> 6, pos = o & 63;
      int ip = pos/9, jp = pos - ip*9;
      int r = ip*2 + tap/3 - 1, c = jp*2 + (tap%3) - 1;
      row = (pos < 54 && r >= 0 && r < 12 && c >= 0 && c < 18) ? (r*18 + c) : 216;
      rmap[o] = (unsigned short)(row*256 + ((row&7)<<4));
    } else {                            // rmapF[win][lw]
      int t = o - 576; int win = t >> 6, lw = t & 63;
      int r0 = (win/3)*6, c0 = (win%3)*6;
      row = (lw < 36) ? ((r0 + lw/6)*18 + c0 + lw%6) : 216;
      rmapF[t] = (unsigned short)(row*256 + ((row&7)<<4));
    }
  }
  __syncthreads();

  // ===================== FINE F1: all 6 windows batched =====================
  for (int task = wvx; task < 18; task += 8){
    int win = task/3, rg = task - win*3;
    unsigned ax = rmapF[win*64 + rg*16 + n16];
    floatx4 acc = {0.f,0.f,0.f,0.f};
    #pragma unroll
    for (int ks=0; ks<4; ks++){
      mfrag a = tfragX(ax, ks*64 + q4*16);
      mfrag bf = zfrag();
      if (n16 < 8) bf = *reinterpret_cast<const mfrag*>(p.U + (win*8+n16)*128 + ks*32 + q4*8);
      acc = mfma16(a, bf, acc);
    }
    if (n16 < 8){
      #pragma unroll
      for (int r=0;r<4;r++){
        int l = rg*16 + q4*4 + r;
        if (l < 36) sfT[(win*8+n16)*40 + l] = acc[r];
      }
    }
  }
  __syncthreads();
  // F2: softmax — 8 waves x 6 rows, shuffle butterflies
  {
    int l = lane;
    for (int rr=0; rr<6; rr++){
      int row = wvx*6 + rr;
      float v = (l < 36) ? sfT[row*40 + l] : -1e30f;
      float mx = v;
      #pragma unroll
      for (int m=1;m<64;m<<=1) mx = fmaxf(mx, __shfl_xor(mx, m));
      float e = (l < 36) ? __expf(v - mx) : 0.f;
      float sm = e;
      #pragma unroll
      for (int m=1;m<64;m<<=1) sm += __shfl_xor(sm, m);
      aw[row*TP2 + l] = f2b(e * (1.f/sm));
    }
  }
  __syncthreads();
  // F3: PV  rbA[win*8+h][d] = sum_l aw[..][l] * T[row(win,l)][d]
  {
    int nt = wvx;
    unsigned c2 = (unsigned)((nt*16 + n16)*2);
    unsigned c2m = c2 & 0x70u, c2l = c2 & 0x8Fu;
    for (int win=0; win<6; win++){
      floatx4 acc={0.f,0.f,0.f,0.f};
      #pragma unroll
      for (int ks=0; ks<2; ks++){
        mfrag a = zfrag();
        if (n16 < 8) a = *reinterpret_cast<const mfrag*>(aw + (win*8+n16)*TP2 + ks*32 + q4*8);
        us8 rv = *reinterpret_cast<const us8*>(rmapF + win*64 + ks*32 + q4*8);
        F8 bb;
        #pragma unroll
        for (int j=0;j<8;j++)
          bb.u[j] = *reinterpret_cast<const unsigned short*>(tB + (((unsigned)rv[j] ^ c2m) + c2l));
        acc = mfma16(a, bb.v, acc);
      }
      #pragma unroll
      for (int r=0;r<4;r++){
        int h = q4*4 + r;
        if (h < 8) rbA[(win*8+h)*TP1 + nt*16 + n16] = f2b(acc[r]);
      }
    }
  }
  __syncthreads();
  // F4 (MFMA vs wvT) + C-score, fused phase (disjoint LDS)
  {
    int h = wvx;
    const unsigned short* wvT = p.wT + 6*16384;
    floatx4 acc = {0.f,0.f,0.f,0.f};
    #pragma unroll
    for (int ks=0; ks<4; ks++){
      mfrag a = zfrag();
      if (n16 < 6) a = *reinterpret_cast<const mfrag*>(rbA + (n16*8+h)*TP1 + ks*32 + q4*8);
      mfrag bf = *reinterpret_cast<const mfrag*>(wvT + (h*16+n16)*128 + ks*32 + q4*8);
      acc = mfma16(a, bf, acc);
    }
    float bvd = p.bv[h*16+n16];
    #pragma unroll
    for (int r=0;r<4;r++){
      int win = q4*4 + r;
      if (win < 6) p.out[((size_t)b*10 + win)*128 + h*16 + n16] = acc[r] + bvd;
    }
  }
  { // C-score: 9 taps from resident tile, acc in regs
    int g = wvx >> 1, nt = wvx & 1;
    int pos = g*16 + n16;
    floatx4 acc = {0.f,0.f,0.f,0.f};
    for (int tap=0; tap<9; tap++){
      unsigned ax = rmap[tap*64 + pos];
      #pragma unroll
      for (int ks=0; ks<4; ks++){
        mfrag a = tfragX(ax, ks*64 + q4*16);
        mfrag bf = *reinterpret_cast<const mfrag*>(
            p.G + (size_t)(tap*32 + nt*16 + n16)*128 + ks*32 + q4*8);
        acc = mfma16(a, bf, acc);
      }
    }
    #pragma unroll
    for (int r=0;r<4;r++){
      int l = g*16 + q4*4 + r;
      if (l < LC) sctT[(nt*16+n16)*56 + l] = acc[r];
    }
  }
  __syncthreads();
  // C2: masked window softmax — 8 waves x 4 rows
  {
    int l = lane;
    int rl = (l < 54) ? (l/9) : 0, cl = (l < 54) ? (l - (l/9)*9) : 0;
    for (int rr=0; rr<4; rr++){
      int ih = wvx*4 + rr;
      int i = ih >> 3;
      int rA = (i>>1)*3, cA = (i&1)*4, cB = (i&1)? 9 : 4;
      bool member = (l < 54) && rl >= rA && rl < rA+3 && cl >= cA && cl < cB;
      float s = member ? sctT[ih*56 + l] : -1e30f;
      float mx = s;
      #pragma unroll
      for (int m=1;m<64;m<<=1) mx = fmaxf(mx, __shfl_xor(mx, m));
      float e = member ? __expf(s - mx) : 0.f;
      float sm = e;
      #pragma unroll
      for (int m=1;m<64;m<<=1) sm += __shfl_xor(sm, m);
      ac[ih*TP2 + l] = f2b(e * (1.f/sm));
    }
  }
  __syncthreads();
  // C3: per tap PV -> rt (double-buffered), proj by cwvT, acc in regs
  {
    floatx4 pacc = {0.f,0.f,0.f,0.f};
    int h = wvx, nt = wvx;
    unsigned c2 = (unsigned)((nt*16 + n16)*2);
    unsigned c2m = c2 & 0x70u, c2l = c2 & 0x8Fu;
    for (int tap=0; tap<9; tap++){
      unsigned short* rtw = (tap & 1) ? rt1 : rt0;
      us8 rv0 = *reinterpret_cast<const us8*>(rmap + tap*64 +      q4*8);
      us8 rv1 = *reinterpret_cast<const us8*>(rmap + tap*64 + 32 + q4*8);
      F8 b0, b1;
      #pragma unroll
      for (int j=0;j<8;j++){
        b0.u[j] = *reinterpret_cast<const unsigned short*>(tB + (((unsigned)rv0[j] ^ c2m) + c2l));
        b1.u[j] = *reinterpret_cast<const unsigned short*>(tB + (((unsigned)rv1[j] ^ c2m) + c2l));
      }
      #pragma unroll
      for (int mt=0; mt<2; mt++){
        mfrag a0 = *reinterpret_cast<const mfrag*>(ac + (mt*16+n16)*TP2 +      q4*8);
        mfrag a1 = *reinterpret_cast<const mfrag*>(ac + (mt*16+n16)*TP2 + 32 + q4*8);
        floatx4 rr = {0.f,0.f,0.f,0.f};
        rr = mfma16(a0, b0.v, rr);
        rr = mfma16(a1, b1.v, rr);
        #pragma unroll
        for (int r=0;r<4;r++){
          int ih = mt*16 + q4*4 + r;
          rtw[ih*TP1 + nt*16 + n16] = f2b(rr[r]);
        }
      }
      __syncthreads();
      #pragma unroll
      for (int ks=0; ks<4; ks++){
        mfrag a = zfrag();
        if (n16 < 4) a = *reinterpret_cast<const mfrag*>(rtw + (n16*8 + h)*TP1 + ks*32 + q4*8);
        mfrag bf = *reinterpret_cast<const mfrag*>(
            p.cwvT + ((size_t)tap*128 + h*16 + n16)*128 + ks*32 + q4*8);
        pacc = mfma16(a, bf, pacc);
      }
    }
    if (q4 == 0){
      #pragma unroll
      for (int r=0;r<4;r++){
        int d = h*16 + n16;
        p.out[((size_t)b*10 + 6 + r)*128 + d] = pacc[r] + p.cvb[d];
      }
    }
  }
}

// ------------------- K2: proj + residual + LN + GELU FFN --------------------
__global__ __launch_bounds__(256) void kffn(Par p){
  __shared__ alignas(16) unsigned short ba[64*TP1];   // bf16 work buffer
  __shared__ alignas(16) unsigned short bbq[64*TP1];  // bf16 work buffer
  __shared__ alignas(16) unsigned short xb[64*TP1];   // bf16 pre-LN residual x
  int tid=threadIdx.x, bid=blockIdx.x;
  int lane=tid&63, wvv=tid>>6, q4=lane>>4, n16=lane&15;
  bool fine = bid < 384;
  int rows0 = fine? bid*64 : (bid-384)*64;
  int TPB = fine? 6 : 4, toff = fine? 0 : 6;
  const unsigned short* w1 = p.wT + (fine?0:3)*16384;
  const unsigned short* w2 = p.wT + (fine?1:4)*16384;
  const unsigned short* w3 = p.wT + (fine?2:5)*16384;
  const float* bi1 = fine? p.bp  : p.bpc;
  const float* bi2 = fine? p.f1b : p.f1cb;
  const float* bi3 = fine? p.f2b : p.f2cb;
  const float* g2  = fine? p.ln2g : p.ln2cg;
  const float* be2 = fine? p.ln2b : p.ln2cb;

  for (int ci=tid; ci<64*32; ci+=256){
    int row=ci>>5, c4=ci&31;
    int grow = rows0 + row;
    int bglob = grow / TPB, t = toff + (grow % TPB);
    float4 v = *reinterpret_cast<const float4*>(p.out + ((size_t)bglob*10+t)*128 + c4*4);
    us4 o = { f2b(v.x), f2b(v.y), f2b(v.z), f2b(v.w) };
    *reinterpret_cast<us4*>(ba + row*TP1 + c4*4) = o;
  }
  __syncthreads();
  { // x = sc + att@wp + bp   (store x as bf16 in xb)
    mfrag A[4];
    #pragma unroll
    for (int ks=0;ks<4;ks++) A[ks] = *reinterpret_cast<const mfrag*>(ba + (wvv*16+n16)*TP1 + ks*32+q4*8);
    for (int nt=0;nt<8;nt++){
      floatx4 acc={0.f,0.f,0.f,0.f};
      #pragma unroll
      for (int ks=0;ks<4;ks++){
        mfrag Bf = *reinterpret_cast<const mfrag*>(w1 + (nt*16+n16)*128 + ks*32+q4*8);
        acc = mfma16(A[ks], Bf, acc);
      }
      #pragma unroll
      for (int r=0;r<4;r++){
        int row = wvv*16+q4*4+r;
        int grow = rows0 + row;
        int t = toff + (grow % TPB);
        int d = nt*16+n16;
        xb[row*TP1+d] = f2b(acc[r] + bi1[d] + p.query[t*128+d]);
      }
    }
  }
  __syncthreads();
  { // LayerNorm over x — 4 waves x 16 rows, shuffle butterflies
    float ga = g2[lane], gb = g2[64+lane];
    float ea = be2[lane], eb = be2[64+lane];
    for (int rr=0; rr<16; rr++){
      int row = wvv*16 + rr;
      float v0 = b2f(xb[row*TP1 + lane]);
      float v1 = b2f(xb[row*TP1 + 64 + lane]);
      float s = v0+v1, sq = v0*v0+v1*v1;
      #pragma unroll
      for (int m=1;m<64;m<<=1){ s += __shfl_xor(s, m); sq += __shfl_xor(sq, m); }
      float mean = s*(1.f/128.f), var = sq*(1.f/128.f) - mean*mean;
      float inv = rsqrtf(var + 1e-5f);
      bbq[row*TP1 + lane]      = f2b((v0-mean)*inv*ga + ea);
      bbq[row*TP1 + 64 + lane] = f2b((v1-mean)*inv*gb + eb);
    }
  }
  __syncthreads();
  { // h = gelu(xn@f1 + b1)
    mfrag A[4];
    #pragma unroll
    for (int ks=0;ks<4;ks++) A[ks] = *reinterpret_cast<const mfrag*>(bbq + (wvv*16+n16)*TP1 + ks*32+q4*8);
    for (int nt=0;nt<8;nt++){
      floatx4 acc={0.f,0.f,0.f,0.f};
      #pragma unroll
      for (int ks=0;ks<4;ks++){
        mfrag Bf = *reinterpret_cast<const mfrag*>(w2 + (nt*16+n16)*128 + ks*32+q4*8);
        acc = mfma16(A[ks], Bf, acc);
      }
      #pragma unroll
      for (int r=0;r<4;r++){
        int row=wvv*16+q4*4+r, d=nt*16+n16;
        float v = acc[r] + bi2[d];
        ba[row*TP1+d] = f2b(0.5f*v*(1.f+erff(v*0.70710678118f)));
      }
    }
  }
  __syncthreads();
  { // out = x + h@f2 + b2   (f32 out)
    mfrag A[4];
    #pragma unroll
    for (int ks=0;ks<4;ks++) A[ks] = *reinterpret_cast<const mfrag*>(ba + (wvv*16+n16)*TP1 + ks*32+q4*8);
    for (int nt=0;nt<8;nt++){
      floatx4 acc={0.f,0.f,0.f,0.f};
      #pragma unroll
      for (int ks=0;ks<4;ks++){
        mfrag Bf = *reinterpret_cast<const mfrag*>(w3 + (nt*16+n16)*128 + ks*32+q4*8);
        acc = mfma16(A[ks], Bf, acc);
      }
      #pragma unroll
      for (int r=0;r<4;r++){
        int row=wvv*16+q4*4+r, d=nt*16+n16;
        int grow=rows0+row;
        int bglob = grow / TPB, t = toff + (grow % TPB);
        p.out[((size_t)bglob*10+t)*128+d] = b2f(xb[row*TP1+d]) + acc[r] + bi3[d];
      }
    }
  }
}

// ---------------------------------------------------------------------------
extern "C" void kernel_launch(void* const* d_in, const int* in_sizes, int n_in,
                              void* d_out, int out_size, void* d_ws, size_t ws_size,
                              hipStream_t stream){
  (void)in_sizes; (void)n_in; (void)out_size; (void)ws_size;
  Par p;
  p.query=(const float*)d_in[0];  p.tgt  =(const float*)d_in[1];
  p.ln1g =(const float*)d_in[2];  p.ln1b =(const float*)d_in[3];
  p.ln2g =(const float*)d_in[4];  p.ln2b =(const float*)d_in[5];
  p.wq   =(const float*)d_in[6];  p.bq   =(const float*)d_in[7];
  p.wk   =(const float*)d_in[8];  /* bk d_in[9] unused (softmax-invariant) */
  p.wv   =(const float*)d_in[10]; p.bv   =(const float*)d_in[11];
  p.wp   =(const float*)d_in[12]; p.bp   =(const float*)d_in[13];
  p.f1w  =(const float*)d_in[14]; p.f1b  =(const float*)d_in[15];
  p.f2w  =(const float*)d_in[16]; p.f2b  =(const float*)d_in[17];
  p.cw   =(const float*)d_in[18]; p.cb   =(const float*)d_in[19];
  p.ln1cg=(const float*)d_in[20]; p.ln1cb=(const float*)d_in[21];
  p.ln2cg=(const float*)d_in[22]; p.ln2cb=(const float*)d_in[23];
  p.wqc  =(const float*)d_in[24]; p.bqc  =(const float*)d_in[25];
  p.wkc  =(const float*)d_in[26]; /* bkc d_in[27] unused */
  p.wvc  =(const float*)d_in[28]; p.bvc  =(const float*)d_in[29];
  p.wpc  =(const float*)d_in[30]; p.bpc  =(const float*)d_in[31];
  p.f1cw =(const float*)d_in[32]; p.f1cb =(const float*)d_in[33];
  p.f2cw =(const float*)d_in[34]; p.f2cb =(const float*)d_in[35];
  char* ws = (char*)d_ws;
  p.U    = (unsigned short*)(ws + 0);        //  12,288 B
  p.uc   = (float*)        (ws + 16384);     //  16,384 B
  p.cvb  = (float*)        (ws + 32768);     //     512 B
  p.G    = (unsigned short*)(ws + 33280);    //  73,728 B -> 107,008
  p.cwvT = (unsigned short*)(ws + 107008);   // 294,912 B -> 401,920
  p.wT   = (unsigned short*)(ws + 401920);   // 8 x 32,768 B -> 664,064
  p.out  = (float*)d_out;

  k0a   <<<dim3(1),    dim3(256), 0, stream>>>(p);
  ktrans<<<dim3(8),    dim3(256), 0, stream>>>(p);
  kfold <<<dim3(18),   dim3(256), 0, stream>>>(p);
  kmain <<<dim3(4096), dim3(512), 0, stream>>>(p);
  kffn  <<<dim3(640),  dim3(256), 0, stream>>>(p);
}